// Round 1
// 1431.055 us; speedup vs baseline: 1.0585x; 1.0585x over previous
//
#include <hip/hip_runtime.h>

#define E_TOTAL 1600000
#define NN 100000
#define D 128      // node dim
#define ED 32      // edge dim
#define H 256      // hidden dim

typedef __attribute__((ext_vector_type(8))) short s16x8;   // 8 bf16 (one MFMA A/B frag)
typedef __attribute__((ext_vector_type(4))) short s16x4;
typedef __attribute__((ext_vector_type(4))) float f32x4;

#define MFMA(a, b, c) __builtin_amdgcn_mfma_f32_16x16x32_bf16((a), (b), (c), 0, 0, 0)

__device__ __forceinline__ short f2bf(float f) {
    unsigned u = __builtin_bit_cast(unsigned, f);
    u += 0x7fffu + ((u >> 16) & 1u);   // round-to-nearest-even
    return (short)(u >> 16);
}

// ---- prep: fp32 x -> bf16 ----
__global__ void k_cvt_x(const float* __restrict__ x, short* __restrict__ xb, int n) {
    int i = (blockIdx.x * blockDim.x + threadIdx.x) * 4;
    if (i >= n) return;
    f32x4 v = *(const f32x4*)(x + i);
    s16x4 o;
    o[0] = f2bf(v[0]); o[1] = f2bf(v[1]); o[2] = f2bf(v[2]); o[3] = f2bf(v[3]);
    *(s16x4*)(xb + i) = o;
}

// ---- prep: swizzle weight [K][N] fp32 into MFMA B-fragment order, bf16 ----
// out[((t*NT + nt)*64 + lane)*8 + j] = W[t*32 + (lane>>4)*8 + j][nt*16 + (lane&15)]
__global__ void k_swz(const float* __restrict__ W, short* __restrict__ out,
                      int K, int N, int total) {
    int idx = blockIdx.x * blockDim.x + threadIdx.x;
    if (idx >= total) return;
    int j    = idx & 7;
    int lane = (idx >> 3) & 63;
    int rest = idx >> 9;                // t*NT + nt
    int NT   = N >> 4;
    int nt   = rest % NT;
    int t    = rest / NT;
    int k    = t * 32 + (lane >> 4) * 8 + j;
    int col  = nt * 16 + (lane & 15);
    float v  = (k < K) ? W[k * N + col] : 0.f;
    out[idx] = f2bf(v);
}

// ---- edge MLP + scatter-add ----
// M=32 per wave: each B-fragment from L2 feeds 2 MFMAs (halves L2 weight stream).
// Block = 128 threads (2 waves x 32 edges = 64 edges/block), hbuf stays 33792 B.
__global__ __launch_bounds__(128, 2)
void k_edge(const short* __restrict__ xb, const int* __restrict__ ei,
            const float* __restrict__ eattr, const float* __restrict__ cong,
            const short* __restrict__ W1s, const float* __restrict__ b1,
            const short* __restrict__ W2s, const float* __restrict__ b2,
            float* __restrict__ agg) {
    __shared__ short hbuf[64][H + 8];   // +8 bf16 = +16B pad: kills LDS bank conflicts
    const int lane = threadIdx.x & 63;
    const int w    = threadIdx.x >> 6;  // wave id (0..1), owns edges [w*32, w*32+32)
    const int m    = lane & 15;
    const int q    = lane >> 4;
    const int e0   = blockIdx.x * 64 + w * 32;
    const int ea   = e0 + m;            // mb=0 edge
    const int eb   = e0 + 16 + m;       // mb=1 edge

    const int src0 = ei[ea];
    const int src1 = ei[eb];
    const int dst0 = ei[E_TOTAL + ea];  // only used to form A-frags; epilogue reloads per-row
    const int dst1 = ei[E_TOTAL + eb];

    // ---- layer 1: [32 x 320] @ [320 x 256] ----
    f32x4 acc[16][2];
#pragma unroll
    for (int n = 0; n < 16; n++) {
        acc[n][0] = (f32x4){0.f, 0.f, 0.f, 0.f};
        acc[n][1] = (f32x4){0.f, 0.f, 0.f, 0.f};
    }

    const short* a0s = xb + (long)src0 * D + q * 8;
    const short* a0d = xb + (long)dst0 * D + q * 8;
    const short* a1s = xb + (long)src1 * D + q * 8;
    const short* a1d = xb + (long)dst1 * D + q * 8;

#pragma unroll
    for (int t = 0; t < 10; t++) {
        s16x8 a0, a1;
        if (t < 4) {
            a0 = *(const s16x8*)(a0s + t * 32);
            a1 = *(const s16x8*)(a1s + t * 32);
        } else if (t < 8) {
            a0 = *(const s16x8*)(a0d + (t - 4) * 32);
            a1 = *(const s16x8*)(a1d + (t - 4) * 32);
        } else if (t == 8) {
            const float* p0 = eattr + (long)ea * ED + q * 8;
            const float* p1 = eattr + (long)eb * ED + q * 8;
            f32x4 v00 = *(const f32x4*)p0, v01 = *(const f32x4*)(p0 + 4);
            f32x4 v10 = *(const f32x4*)p1, v11 = *(const f32x4*)(p1 + 4);
#pragma unroll
            for (int j = 0; j < 4; j++) {
                a0[j] = f2bf(v00[j]); a0[4 + j] = f2bf(v01[j]);
                a1[j] = f2bf(v10[j]); a1[4 + j] = f2bf(v11[j]);
            }
        } else {
            a0 = (s16x8){0, 0, 0, 0, 0, 0, 0, 0};
            a1 = (s16x8){0, 0, 0, 0, 0, 0, 0, 0};
            if (q == 0) {                       // k=288 is the congestion feature
                a0[0] = f2bf(cong[src0]);
                a1[0] = f2bf(cong[src1]);
            }
        }
        const short* wp = W1s + (t * 16) * 512 + lane * 8;
#pragma unroll
        for (int n = 0; n < 16; n++) {
            s16x8 b = *(const s16x8*)(wp + n * 512);
            acc[n][0] = MFMA(a0, b, acc[n][0]);
            acc[n][1] = MFMA(a1, b, acc[n][1]);
        }
    }

    // epilogue 1: +bias, relu, bf16 -> LDS (C-layout -> A-layout transform)
#pragma unroll
    for (int n = 0; n < 16; n++) {
        int col = n * 16 + m;
        float bias = b1[col];
#pragma unroll
        for (int mb = 0; mb < 2; mb++) {
#pragma unroll
            for (int r = 0; r < 4; r++) {
                int row = w * 32 + mb * 16 + q * 4 + r;
                float v = acc[n][mb][r] + bias;
                hbuf[row][col] = f2bf(v > 0.f ? v : 0.f);
            }
        }
    }
    // wave-private rows: no __syncthreads needed (compiler inserts lgkmcnt waits)

    // ---- layer 2: [32 x 256] @ [256 x 128] ----
    f32x4 acc2[8][2];
#pragma unroll
    for (int n = 0; n < 8; n++) {
        acc2[n][0] = (f32x4){0.f, 0.f, 0.f, 0.f};
        acc2[n][1] = (f32x4){0.f, 0.f, 0.f, 0.f};
    }
#pragma unroll
    for (int t = 0; t < 8; t++) {
        s16x8 a0 = *(const s16x8*)&hbuf[w * 32 + m][t * 32 + q * 8];
        s16x8 a1 = *(const s16x8*)&hbuf[w * 32 + 16 + m][t * 32 + q * 8];
        const short* wp = W2s + (t * 8) * 512 + lane * 8;
#pragma unroll
        for (int n = 0; n < 8; n++) {
            s16x8 b = *(const s16x8*)(wp + n * 512);
            acc2[n][0] = MFMA(a0, b, acc2[n][0]);
            acc2[n][1] = MFMA(a1, b, acc2[n][1]);
        }
    }

    // epilogue 2: +bias, atomic scatter-add into agg[dst]
#pragma unroll
    for (int mb = 0; mb < 2; mb++) {
#pragma unroll
        for (int r = 0; r < 4; r++) {
            int row = mb * 16 + q * 4 + r;
            int d   = ei[E_TOTAL + e0 + row];   // same for all 16 lanes of this quad
            float* ap = agg + (long)d * D + m;
#pragma unroll
            for (int n = 0; n < 8; n++) {
                float v = acc2[n][mb][r] + b2[n * 16 + m];
                __hip_atomic_fetch_add(ap + n * 16, v, __ATOMIC_RELAXED, __HIP_MEMORY_SCOPE_AGENT);
            }
        }
    }
}

// ---- node MLP (same M=32/wave structure) ----
__global__ __launch_bounds__(128, 2)
void k_node(const short* __restrict__ xb, const float* __restrict__ agg,
            const short* __restrict__ U1s, const float* __restrict__ b1,
            const short* __restrict__ U2s, const float* __restrict__ b2,
            float* __restrict__ out) {
    __shared__ short hbuf[64][H + 8];
    const int lane = threadIdx.x & 63;
    const int w    = threadIdx.x >> 6;
    const int m    = lane & 15;
    const int q    = lane >> 4;
    const int r0   = blockIdx.x * 64 + w * 32;
    int rowa = r0 + m;
    int rowb = r0 + 16 + m;
    int rca  = rowa < NN ? rowa : 0;    // clamp gathers; stores are guarded
    int rcb  = rowb < NN ? rowb : 0;

    f32x4 acc[16][2];
#pragma unroll
    for (int n = 0; n < 16; n++) {
        acc[n][0] = (f32x4){0.f, 0.f, 0.f, 0.f};
        acc[n][1] = (f32x4){0.f, 0.f, 0.f, 0.f};
    }

#pragma unroll
    for (int t = 0; t < 8; t++) {
        s16x8 a0, a1;
        if (t < 4) {
            a0 = *(const s16x8*)(xb + (long)rca * D + t * 32 + q * 8);
            a1 = *(const s16x8*)(xb + (long)rcb * D + t * 32 + q * 8);
        } else {
            const float* p0 = agg + (long)rca * D + (t - 4) * 32 + q * 8;
            const float* p1 = agg + (long)rcb * D + (t - 4) * 32 + q * 8;
            f32x4 v00 = *(const f32x4*)p0, v01 = *(const f32x4*)(p0 + 4);
            f32x4 v10 = *(const f32x4*)p1, v11 = *(const f32x4*)(p1 + 4);
#pragma unroll
            for (int j = 0; j < 4; j++) {
                a0[j] = f2bf(v00[j]); a0[4 + j] = f2bf(v01[j]);
                a1[j] = f2bf(v10[j]); a1[4 + j] = f2bf(v11[j]);
            }
        }
        const short* wp = U1s + (t * 16) * 512 + lane * 8;
#pragma unroll
        for (int n = 0; n < 16; n++) {
            s16x8 b = *(const s16x8*)(wp + n * 512);
            acc[n][0] = MFMA(a0, b, acc[n][0]);
            acc[n][1] = MFMA(a1, b, acc[n][1]);
        }
    }

#pragma unroll
    for (int n = 0; n < 16; n++) {
        int col = n * 16 + m;
        float bias = b1[col];
#pragma unroll
        for (int mb = 0; mb < 2; mb++) {
#pragma unroll
            for (int r = 0; r < 4; r++) {
                int row = w * 32 + mb * 16 + q * 4 + r;
                float v = acc[n][mb][r] + bias;
                hbuf[row][col] = f2bf(v > 0.f ? v : 0.f);
            }
        }
    }

    f32x4 acc2[8][2];
#pragma unroll
    for (int n = 0; n < 8; n++) {
        acc2[n][0] = (f32x4){0.f, 0.f, 0.f, 0.f};
        acc2[n][1] = (f32x4){0.f, 0.f, 0.f, 0.f};
    }
#pragma unroll
    for (int t = 0; t < 8; t++) {
        s16x8 a0 = *(const s16x8*)&hbuf[w * 32 + m][t * 32 + q * 8];
        s16x8 a1 = *(const s16x8*)&hbuf[w * 32 + 16 + m][t * 32 + q * 8];
        const short* wp = U2s + (t * 8) * 512 + lane * 8;
#pragma unroll
        for (int n = 0; n < 8; n++) {
            s16x8 b = *(const s16x8*)(wp + n * 512);
            acc2[n][0] = MFMA(a0, b, acc2[n][0]);
            acc2[n][1] = MFMA(a1, b, acc2[n][1]);
        }
    }

#pragma unroll
    for (int mb = 0; mb < 2; mb++) {
#pragma unroll
        for (int r = 0; r < 4; r++) {
            int orow = r0 + mb * 16 + q * 4 + r;
            if (orow < NN) {
#pragma unroll
                for (int n = 0; n < 8; n++) {
                    out[(long)orow * D + n * 16 + m] = acc2[n][mb][r] + b2[n * 16 + m];
                }
            }
        }
    }
}

extern "C" void kernel_launch(void* const* d_in, const int* in_sizes, int n_in,
                              void* d_out, int out_size, void* d_ws, size_t ws_size,
                              hipStream_t stream) {
    const float* x     = (const float*)d_in[0];
    const int*   ei    = (const int*)d_in[1];
    const float* eattr = (const float*)d_in[2];
    const float* cong  = (const float*)d_in[3];
    const float* mW1   = (const float*)d_in[4];
    const float* mb1   = (const float*)d_in[5];
    const float* mW2   = (const float*)d_in[6];
    const float* mb2   = (const float*)d_in[7];
    const float* uW1   = (const float*)d_in[8];
    const float* ub1   = (const float*)d_in[9];
    const float* uW2   = (const float*)d_in[10];
    const float* ub2   = (const float*)d_in[11];

    char* ws = (char*)d_ws;
    float* agg = (float*)ws;                        // 51,200,000 B
    short* xb  = (short*)(ws + 51200000);           // 25,600,000 B
    short* W1s = (short*)(ws + 76800000);           //    163,840 B (K padded 289->320)
    short* W2s = (short*)(ws + 76963840);           //     65,536 B
    short* U1s = (short*)(ws + 77029376);           //    131,072 B
    short* U2s = (short*)(ws + 77160448);           //     65,536 B  (total ~77.2 MB)

    hipMemsetAsync(agg, 0, (size_t)NN * D * sizeof(float), stream);
    k_cvt_x<<<(NN * D / 4 + 255) / 256, 256, 0, stream>>>(x, xb, NN * D);

    int tW1 = 10 * 16 * 512, tW2 = 8 * 8 * 512, tU1 = 8 * 16 * 512, tU2 = 8 * 8 * 512;
    k_swz<<<(tW1 + 255) / 256, 256, 0, stream>>>(mW1, W1s, 289, 256, tW1);
    k_swz<<<(tW2 + 255) / 256, 256, 0, stream>>>(mW2, W2s, 256, 128, tW2);
    k_swz<<<(tU1 + 255) / 256, 256, 0, stream>>>(uW1, U1s, 256, 256, tU1);
    k_swz<<<(tU2 + 255) / 256, 256, 0, stream>>>(uW2, U2s, 256, 128, tU2);

    // 64 edges / 64 rows per 128-thread block (2 waves x 32)
    k_edge<<<E_TOTAL / 64, 128, 0, stream>>>(xb, ei, eattr, cong, W1s, mb1, W2s, mb2, agg);
    k_node<<<(NN + 63) / 64, 128, 0, stream>>>(xb, agg, U1s, ub1, U2s, ub2, (float*)d_out);
}